// Round 3
// baseline (202.446 us; speedup 1.0000x reference)
//
#include <hip/hip_runtime.h>
#include <hip/hip_bf16.h>

typedef __bf16 bf16x8 __attribute__((ext_vector_type(8)));
typedef float  f32x4  __attribute__((ext_vector_type(4)));

#define LQ 4096
#define LKK 4096
#define DH 64
#define KBLK 64
#define QBLK 64
#define NIT (LKK / KBLK)        /* 64 KV tiles */
#define NB 4                    /* batch */
#define GR_TILE 512             /* 16B granules per 64x64 bf16 tile */
#define ARR_ELEMS ((size_t)NB * NIT * GR_TILE * 8)   /* 1,048,576 per array */
#define WS_NEED (4 * ARR_ELEMS * sizeof(__bf16))     /* 8 MB */

union BFU { unsigned short u; __bf16 b; };
__device__ __forceinline__ __bf16 u2bf(unsigned short v) { BFU x; x.u = v; return x.b; }
__device__ __forceinline__ unsigned short bf2u(__bf16 b) { BFU x; x.b = b; return x.u; }

typedef const __attribute__((address_space(1))) void* gas1_t;
typedef __attribute__((address_space(3))) void* las3_t;
__device__ __forceinline__ void gload_lds16(const void* g, void* l) {
    __builtin_amdgcn_global_load_lds((gas1_t)g, (las3_t)l, 16, 0, 0);
}

// ---------------------------------------------------------------------------
// Fragment-linear layout (granule = 16B = the exact ds_read_b128 of one lane):
//   K granule G=(kb*2+c)*64+ln, elem j = K[16*kb + ll][32*c + 8*gg + j]   (B-op of QK^T)
//   V granule G=(db*2+c)*64+ln, elem j = V[32*c + 8*gg + j][16*db + ll]   (B-op of PV)
// with gg=ln>>4, ll=ln&15.  LDS reads AND global_load_lds staging are
// lane-linear -> conflict-free by construction.
//
// PSM (per-wave P transpose, logical [row=q 0..15][col=key 0..63] of u32
// hi|lo bf16 pairs): physical = row*64 + ((col>>2 + row)&15)*4 + (col&3).
//   writes (fixed kb,r; lanes g,l15): banks hit all-32 exactly 2x/phase -> free
//   reads: per lane two aligned ds_read_b128; bank-quads spread within each
//          16-lane phase -> conflict-free.
// ---------------------------------------------------------------------------

// Pre-pass: convert K,V fp32 -> hi/lo bf16 fragment-linear arrays in ws ONCE
// (removes the 64x per-q-tile-block redundant convert of the naive design).
__global__ __launch_bounds__(256)
void prepack(const float* __restrict__ Kg, const float* __restrict__ Vg,
             __bf16* __restrict__ ws)
{
    __bf16* KHI = ws;
    __bf16* KLO = ws + ARR_ELEMS;
    __bf16* VHI = ws + 2 * ARR_ELEMS;
    __bf16* VLO = ws + 3 * ARR_ELEMS;

    const int gid = blockIdx.x * 256 + threadIdx.x;   // [0, 262144)
    const int isV = gid >> 17;
    const int t   = gid & 131071;
    const int b   = t >> 15;
    const int rem = t & 32767;
    const int kt  = rem >> 9;
    const int G   = rem & 511;
    const int blk = G >> 7;           // kb (K) or db (V)
    const int c   = (G >> 6) & 1;
    const int gg  = (G >> 4) & 3;
    const int ll  = G & 15;

    const size_t dst = ((size_t)(b * NIT + kt) * GR_TILE + G) * 8;
    float x[8];
    if (!isV) {
        const float* src = Kg + ((size_t)b * LKK + kt * KBLK + 16 * blk + ll) * DH + 32 * c + 8 * gg;
        float4 a0 = *(const float4*)src;
        float4 a1 = *(const float4*)(src + 4);
        x[0]=a0.x; x[1]=a0.y; x[2]=a0.z; x[3]=a0.w;
        x[4]=a1.x; x[5]=a1.y; x[6]=a1.z; x[7]=a1.w;
        bf16x8 h, l;
#pragma unroll
        for (int j = 0; j < 8; ++j) {
            __bf16 hh = (__bf16)x[j];
            h[j] = hh; l[j] = (__bf16)(x[j] - (float)hh);
        }
        *(bf16x8*)&KHI[dst] = h;  *(bf16x8*)&KLO[dst] = l;
    } else {
        const float* src = Vg + ((size_t)b * LKK + kt * KBLK + 32 * c + 8 * gg) * DH + 16 * blk + ll;
#pragma unroll
        for (int j = 0; j < 8; ++j) x[j] = src[(size_t)j * DH];
        bf16x8 h, l;
#pragma unroll
        for (int j = 0; j < 8; ++j) {
            __bf16 hh = (__bf16)x[j];
            h[j] = hh; l[j] = (__bf16)(x[j] - (float)hh);
        }
        *(bf16x8*)&VHI[dst] = h;  *(bf16x8*)&VLO[dst] = l;
    }
}

// Main flash kernel: consumes pre-converted tiles via global_load_lds dbuf.
__global__ __launch_bounds__(256, 1)
void attn_fwd_pre(const float* __restrict__ Qg, const __bf16* __restrict__ ws,
                  float* __restrict__ Og)
{
    // XCD swizzle: blocks round-robin over 8 XCDs; batch = (bid>>1)&3 pins each
    // batch's 2MB packed KV to one XCD pair's L2 (4MB each).
    const int bid = blockIdx.x;
    const int bz  = (bid >> 1) & 3;
    const int qt  = ((bid & 1) << 5) | (bid >> 3);
    const int tid  = threadIdx.x;
    const int w    = tid >> 6;
    const int lane = tid & 63;
    const int g    = lane >> 4;
    const int l15  = lane & 15;
    const int q0   = qt * QBLK + w * 16;

    __shared__ __align__(16) __bf16 TILES[2][4][GR_TILE * 8];     // 64 KB
    __shared__ __align__(16) unsigned int PSM[4][16 * 64];        // 16 KB

    const __bf16* wsA[4] = { ws, ws + ARR_ELEMS, ws + 2 * ARR_ELEMS, ws + 3 * ARR_ELEMS };

    const size_t bqoff = (size_t)bz * LQ * DH;

    // Q fragments: scale then hi/lo split (once per block)
    bf16x8 qhi[2], qlo[2];
#pragma unroll
    for (int c = 0; c < 2; ++c) {
        const float* src = Qg + bqoff + (size_t)(q0 + l15) * DH + 32 * c + 8 * g;
#pragma unroll
        for (int j = 0; j < 8; ++j) {
            float x = src[j] * 0.125f;
            __bf16 h = (__bf16)x;
            qhi[c][j] = h;
            qlo[c][j] = (__bf16)(x - (float)h);
        }
    }

    auto STAGE = [&](int buf, int kt) {
        const size_t toff = (size_t)(bz * NIT + kt) * GR_TILE * 8;
#pragma unroll
        for (int a = 0; a < 4; ++a) {
            const __bf16* src = wsA[a] + toff + (size_t)(w * 128 + lane) * 8;
            __bf16* dst = &TILES[buf][a][w * 128 * 8];
            gload_lds16(src, dst);
            gload_lds16(src + 64 * 8, dst + 64 * 8);
        }
    };

    f32x4 oacc[4] = {};
    float m_run[4], l_run[4];
#pragma unroll
    for (int r = 0; r < 4; ++r) { m_run[r] = -1e30f; l_run[r] = 0.f; }

    STAGE(0, 0);
    __syncthreads();                    // drains vmcnt + syncs: tile 0 staged

    int cur = 0;
    for (int kt = 0; kt < NIT; ++kt) {
        if (kt + 1 < NIT) STAGE(cur ^ 1, kt + 1);   // prefetch under compute

        const __bf16* KHI_l = TILES[cur][0];
        const __bf16* KLO_l = TILES[cur][1];
        const __bf16* VHI_l = TILES[cur][2];
        const __bf16* VLO_l = TILES[cur][3];

        // ---- S = (Q*scale) K^T, 3-term hi/lo split ----
        f32x4 s[4] = {};
        __builtin_amdgcn_s_setprio(1);
#pragma unroll
        for (int kb = 0; kb < 4; ++kb) {
#pragma unroll
            for (int c = 0; c < 2; ++c) {
                bf16x8 kh = *(const bf16x8*)&KHI_l[((kb * 2 + c) * 64 + lane) * 8];
                bf16x8 kl = *(const bf16x8*)&KLO_l[((kb * 2 + c) * 64 + lane) * 8];
                s[kb] = __builtin_amdgcn_mfma_f32_16x16x32_bf16(qhi[c], kh, s[kb], 0, 0, 0);
                s[kb] = __builtin_amdgcn_mfma_f32_16x16x32_bf16(qlo[c], kh, s[kb], 0, 0, 0);
                s[kb] = __builtin_amdgcn_mfma_f32_16x16x32_bf16(qhi[c], kl, s[kb], 0, 0, 0);
            }
        }
        __builtin_amdgcn_s_setprio(0);

        // ---- online softmax (rows live on 16-lane groups; wave-parallel) ----
        float tmax[4];
#pragma unroll
        for (int r = 0; r < 4; ++r)
            tmax[r] = fmaxf(fmaxf(s[0][r], s[1][r]), fmaxf(s[2][r], s[3][r]));
#pragma unroll
        for (int off = 1; off < 16; off <<= 1)
#pragma unroll
            for (int r = 0; r < 4; ++r)
                tmax[r] = fmaxf(tmax[r], __shfl_xor(tmax[r], off, 64));

        float alpha[4], psum[4];
#pragma unroll
        for (int r = 0; r < 4; ++r) {
            float mnew = fmaxf(m_run[r], tmax[r]);
            alpha[r] = __expf(m_run[r] - mnew);
            m_run[r] = mnew;
            psum[r] = 0.f;
        }
#pragma unroll
        for (int kb = 0; kb < 4; ++kb)
#pragma unroll
            for (int r = 0; r < 4; ++r) {
                float p = __expf(s[kb][r] - m_run[r]);
                s[kb][r] = p;
                psum[r] += p;
            }
#pragma unroll
        for (int off = 1; off < 16; off <<= 1)
#pragma unroll
            for (int r = 0; r < 4; ++r)
                psum[r] += __shfl_xor(psum[r], off, 64);
#pragma unroll
        for (int r = 0; r < 4; ++r) {
            l_run[r] = l_run[r] * alpha[r] + psum[r];
#pragma unroll
            for (int db = 0; db < 4; ++db) oacc[db][r] *= alpha[r];
        }

        // ---- P -> PSM (hi|lo packed u32), granule-rotated layout ----
        // logical row = 4g+r (q), col = 16kb+l15 (key)
#pragma unroll
        for (int kb = 0; kb < 4; ++kb)
#pragma unroll
            for (int r = 0; r < 4; ++r) {
                float p = s[kb][r];
                __bf16 h = (__bf16)p;
                __bf16 l = (__bf16)(p - (float)h);
                const int row = 4 * g + r;
                const int idx = row * 64 + (((4 * kb + (l15 >> 2) + row) & 15) << 2) + (l15 & 3);
                PSM[w][idx] = (unsigned int)bf2u(h) | ((unsigned int)bf2u(l) << 16);
            }

        // ---- O += P V, 3-term split (P frag: row=l15 q, k=32c+8g+j key) ----
#pragma unroll
        for (int c = 0; c < 2; ++c) {
            const unsigned int* prow = &PSM[w][l15 * 64];
            const int qg = 2 * g + 8 * c;
            uint4 ulo = *(const uint4*)&prow[((qg + l15) & 15) << 2];
            uint4 uhi = *(const uint4*)&prow[((qg + 1 + l15) & 15) << 2];
            unsigned int uu[8] = { ulo.x, ulo.y, ulo.z, ulo.w, uhi.x, uhi.y, uhi.z, uhi.w };
            bf16x8 ph, pl;
#pragma unroll
            for (int j = 0; j < 8; ++j) {
                ph[j] = u2bf((unsigned short)(uu[j] & 0xffffu));
                pl[j] = u2bf((unsigned short)(uu[j] >> 16));
            }
            __builtin_amdgcn_s_setprio(1);
#pragma unroll
            for (int db = 0; db < 4; ++db) {
                bf16x8 vh = *(const bf16x8*)&VHI_l[((db * 2 + c) * 64 + lane) * 8];
                bf16x8 vl = *(const bf16x8*)&VLO_l[((db * 2 + c) * 64 + lane) * 8];
                oacc[db] = __builtin_amdgcn_mfma_f32_16x16x32_bf16(ph, vh, oacc[db], 0, 0, 0);
                oacc[db] = __builtin_amdgcn_mfma_f32_16x16x32_bf16(ph, vl, oacc[db], 0, 0, 0);
                oacc[db] = __builtin_amdgcn_mfma_f32_16x16x32_bf16(pl, vh, oacc[db], 0, 0, 0);
            }
            __builtin_amdgcn_s_setprio(0);
        }

        __syncthreads();   // all reads of cur done AND staged kt+1 drained
        cur ^= 1;
    }

    // ---- epilogue: O = acc / l ----
#pragma unroll
    for (int r = 0; r < 4; ++r) {
        float inv = 1.0f / l_run[r];
#pragma unroll
        for (int db = 0; db < 4; ++db)
            Og[bqoff + (size_t)(q0 + 4 * g + r) * DH + 16 * db + l15] = oacc[db][r] * inv;
    }
}

// ---------------- fallback (self-contained, used only if ws too small) ------
__global__ __launch_bounds__(256, 1)
void attn_fwd_fb(const float* __restrict__ Qg, const float* __restrict__ Kg,
                 const float* __restrict__ Vg, float* __restrict__ Og)
{
    const int bid = blockIdx.x;
    const int bz  = (bid >> 1) & 3;
    const int qt  = ((bid & 1) << 5) | (bid >> 3);
    const int tid  = threadIdx.x;
    const int w    = tid >> 6;
    const int lane = tid & 63;
    const int g    = lane >> 4;
    const int l15  = lane & 15;
    const int q0 = qt * QBLK + w * 16;

    __shared__ __bf16 KHI[512 * 8];
    __shared__ __bf16 KLO[512 * 8];
    __shared__ __bf16 VHI[512 * 8];
    __shared__ __bf16 VLO[512 * 8];
    __shared__ unsigned int PSM[4][16 * 65];

    const size_t bqoff = (size_t)bz * LQ  * DH;
    const size_t bkoff = (size_t)bz * LKK * DH;

    bf16x8 qhi[2], qlo[2];
#pragma unroll
    for (int c = 0; c < 2; ++c) {
        const float* src = Qg + bqoff + (size_t)(q0 + l15) * DH + 32 * c + 8 * g;
#pragma unroll
        for (int j = 0; j < 8; ++j) {
            float x = src[j] * 0.125f;
            __bf16 h = (__bf16)x;
            qhi[c][j] = h;
            qlo[c][j] = (__bf16)(x - (float)h);
        }
    }

    float4 kreg[4];
    float  vreg[16];

    auto LOADK = [&](int kt) {
#pragma unroll
        for (int gi = 0; gi < 2; ++gi) {
            int G = tid + gi * 256;
            int kb = G >> 7, cc = (G >> 6) & 1, ln = G & 63;
            int gg = ln >> 4, ll = ln & 15;
            const float* src = Kg + bkoff + (size_t)(kt * KBLK + ll + 16 * kb) * DH + 32 * cc + 8 * gg;
            kreg[2 * gi + 0] = *(const float4*)(src);
            kreg[2 * gi + 1] = *(const float4*)(src + 4);
        }
    };
    auto LOADV = [&](int kt) {
#pragma unroll
        for (int gi = 0; gi < 2; ++gi) {
            int G = tid + gi * 256;
            int db = G >> 7, cc = (G >> 6) & 1, ln = G & 63;
            int gg = ln >> 4, ll = ln & 15;
            const float* src = Vg + bkoff + (size_t)(kt * KBLK + 32 * cc + 8 * gg) * DH + 16 * db + ll;
#pragma unroll
            for (int j = 0; j < 8; ++j) vreg[8 * gi + j] = src[(size_t)j * DH];
        }
    };
    auto STORE = [&]() {
#pragma unroll
        for (int gi = 0; gi < 2; ++gi) {
            int G = tid + gi * 256;
            const float* kf = (const float*)&kreg[2 * gi];
            bf16x8 h, l;
#pragma unroll
            for (int j = 0; j < 8; ++j) {
                __bf16 hh = (__bf16)kf[j];
                h[j] = hh; l[j] = (__bf16)(kf[j] - (float)hh);
            }
            *(bf16x8*)&KHI[G * 8] = h;  *(bf16x8*)&KLO[G * 8] = l;
#pragma unroll
            for (int j = 0; j < 8; ++j) {
                float x = vreg[8 * gi + j];
                __bf16 hh = (__bf16)x;
                h[j] = hh; l[j] = (__bf16)(x - (float)hh);
            }
            *(bf16x8*)&VHI[G * 8] = h;  *(bf16x8*)&VLO[G * 8] = l;
        }
    };

    f32x4 oacc[4] = {};
    float m_run[4], l_run[4];
#pragma unroll
    for (int r = 0; r < 4; ++r) { m_run[r] = -1e30f; l_run[r] = 0.f; }

    LOADK(0); LOADV(0);
    STORE();

    for (int kt = 0; kt < NIT; ++kt) {
        __syncthreads();
        if (kt + 1 < NIT) { LOADK(kt + 1); LOADV(kt + 1); }

        f32x4 s[4] = {};
#pragma unroll
        for (int kb = 0; kb < 4; ++kb) {
#pragma unroll
            for (int c = 0; c < 2; ++c) {
                bf16x8 kh = *(const bf16x8*)&KHI[((kb * 2 + c) * 64 + lane) * 8];
                bf16x8 kl = *(const bf16x8*)&KLO[((kb * 2 + c) * 64 + lane) * 8];
                s[kb] = __builtin_amdgcn_mfma_f32_16x16x32_bf16(qhi[c], kh, s[kb], 0, 0, 0);
                s[kb] = __builtin_amdgcn_mfma_f32_16x16x32_bf16(qlo[c], kh, s[kb], 0, 0, 0);
                s[kb] = __builtin_amdgcn_mfma_f32_16x16x32_bf16(qhi[c], kl, s[kb], 0, 0, 0);
            }
        }

        float tmax[4];
#pragma unroll
        for (int r = 0; r < 4; ++r)
            tmax[r] = fmaxf(fmaxf(s[0][r], s[1][r]), fmaxf(s[2][r], s[3][r]));
#pragma unroll
        for (int off = 1; off < 16; off <<= 1)
#pragma unroll
            for (int r = 0; r < 4; ++r)
                tmax[r] = fmaxf(tmax[r], __shfl_xor(tmax[r], off, 64));

        float alpha[4], psum[4];
#pragma unroll
        for (int r = 0; r < 4; ++r) {
            float mnew = fmaxf(m_run[r], tmax[r]);
            alpha[r] = __expf(m_run[r] - mnew);
            m_run[r] = mnew;
            psum[r] = 0.f;
        }
#pragma unroll
        for (int kb = 0; kb < 4; ++kb)
#pragma unroll
            for (int r = 0; r < 4; ++r) {
                float p = __expf(s[kb][r] - m_run[r]);
                s[kb][r] = p;
                psum[r] += p;
            }
#pragma unroll
        for (int off = 1; off < 16; off <<= 1)
#pragma unroll
            for (int r = 0; r < 4; ++r)
                psum[r] += __shfl_xor(psum[r], off, 64);
#pragma unroll
        for (int r = 0; r < 4; ++r) {
            l_run[r] = l_run[r] * alpha[r] + psum[r];
#pragma unroll
            for (int db = 0; db < 4; ++db) oacc[db][r] *= alpha[r];
        }

#pragma unroll
        for (int kb = 0; kb < 4; ++kb)
#pragma unroll
            for (int r = 0; r < 4; ++r) {
                float p = s[kb][r];
                __bf16 h = (__bf16)p;
                __bf16 l = (__bf16)(p - (float)h);
                PSM[w][(4 * g + r) * 65 + l15 + 16 * kb] =
                    (unsigned int)bf2u(h) | ((unsigned int)bf2u(l) << 16);
            }

#pragma unroll
        for (int c = 0; c < 2; ++c) {
            bf16x8 ph, pl;
#pragma unroll
            for (int j = 0; j < 8; ++j) {
                unsigned int u = PSM[w][l15 * 65 + 32 * c + 8 * g + j];
                ph[j] = u2bf((unsigned short)(u & 0xffffu));
                pl[j] = u2bf((unsigned short)(u >> 16));
            }
#pragma unroll
            for (int db = 0; db < 4; ++db) {
                bf16x8 vh = *(const bf16x8*)&VHI[((db * 2 + c) * 64 + lane) * 8];
                bf16x8 vl = *(const bf16x8*)&VLO[((db * 2 + c) * 64 + lane) * 8];
                oacc[db] = __builtin_amdgcn_mfma_f32_16x16x32_bf16(ph, vh, oacc[db], 0, 0, 0);
                oacc[db] = __builtin_amdgcn_mfma_f32_16x16x32_bf16(ph, vl, oacc[db], 0, 0, 0);
                oacc[db] = __builtin_amdgcn_mfma_f32_16x16x32_bf16(pl, vh, oacc[db], 0, 0, 0);
            }
        }

        __syncthreads();
        if (kt + 1 < NIT) STORE();
    }

#pragma unroll
    for (int r = 0; r < 4; ++r) {
        float inv = 1.0f / l_run[r];
#pragma unroll
        for (int db = 0; db < 4; ++db)
            Og[bqoff + (size_t)(q0 + 4 * g + r) * DH + 16 * db + l15] = oacc[db][r] * inv;
    }
}

extern "C" void kernel_launch(void* const* d_in, const int* in_sizes, int n_in,
                              void* d_out, int out_size, void* d_ws, size_t ws_size,
                              hipStream_t stream) {
    (void)in_sizes; (void)n_in; (void)out_size;
    const float* Q = (const float*)d_in[0];
    const float* K = (const float*)d_in[1];
    const float* V = (const float*)d_in[2];
    float* O = (float*)d_out;

    if (ws_size >= WS_NEED) {
        __bf16* ws = (__bf16*)d_ws;
        prepack<<<dim3(1024), dim3(256), 0, stream>>>(K, V, ws);
        attn_fwd_pre<<<dim3(256), dim3(256), 0, stream>>>(Q, ws, O);
    } else {
        attn_fwd_fb<<<dim3(256), dim3(256), 0, stream>>>(Q, K, V, O);
    }
}

// Round 6
// 157.490 us; speedup vs baseline: 1.2855x; 1.2855x over previous
//
#include <hip/hip_runtime.h>
#include <hip/hip_bf16.h>

typedef __bf16 bf16x8 __attribute__((ext_vector_type(8)));
typedef float  f32x4  __attribute__((ext_vector_type(4)));

#define LQ 4096
#define LKK 4096
#define DH 64
#define KBLK 64
#define QBLK 64
#define NIT (LKK / KBLK)        /* 64 KV tiles */
#define NB 4                    /* batch */
#define GR_TILE 512             /* 16B granules per 64x64 bf16 tile */
#define ARR_ELEMS ((size_t)NB * NIT * GR_TILE * 8)   /* 1,048,576 per array */
#define KV_BYTES (4 * ARR_ELEMS * sizeof(__bf16))    /* 8 MB packed KV */
#define PO_BYTES ((size_t)512 * 4096 * sizeof(float))   /* 8 MB partial O */
#define PML_BYTES ((size_t)512 * 128 * sizeof(float))   /* 256 KB m,l */
#define WS_SPLIT (KV_BYTES + PO_BYTES + PML_BYTES)      /* 16.25 MB */
#define WS_SINGLE KV_BYTES

union BFU { unsigned short u; __bf16 b; };
__device__ __forceinline__ __bf16 u2bf(unsigned short v) { BFU x; x.u = v; return x.b; }
__device__ __forceinline__ unsigned short bf2u(__bf16 b) { BFU x; x.b = b; return x.u; }

typedef const __attribute__((address_space(1))) void* gas1_t;
typedef __attribute__((address_space(3))) void* las3_t;
__device__ __forceinline__ void gload_lds16(const void* g, void* l) {
    __builtin_amdgcn_global_load_lds((gas1_t)g, (las3_t)l, 16, 0, 0);
}

// ---------------------------------------------------------------------------
// Fragment-linear layout (granule = 16B = one lane's ds_read_b128):
//   K granule G=(kb*2+c)*64+ln, elem j = K[16*kb + ll][32*c + 8*gg + j]
//   V granule G=(db*2+c)*64+ln, elem j = V[32*c + 8*gg + j][16*db + ll]
// with gg=ln>>4, ll=ln&15.  LDS reads AND global_load_lds staging lane-linear.
// PSM: physical = row*64 + ((col>>2 + row)&15)*4 + (col&3)  (conflict-free
// writes by 32-lane phase; aligned b128 reads).
// ---------------------------------------------------------------------------

__global__ __launch_bounds__(256)
void prepack(const float* __restrict__ Kg, const float* __restrict__ Vg,
             __bf16* __restrict__ ws)
{
    __bf16* KHI = ws;
    __bf16* KLO = ws + ARR_ELEMS;
    __bf16* VHI = ws + 2 * ARR_ELEMS;
    __bf16* VLO = ws + 3 * ARR_ELEMS;

    const int gid = blockIdx.x * 256 + threadIdx.x;   // [0, 262144)
    const int isV = gid >> 17;
    const int t   = gid & 131071;
    const int b   = t >> 15;
    const int rem = t & 32767;
    const int kt  = rem >> 9;
    const int G   = rem & 511;
    const int blk = G >> 7;
    const int c   = (G >> 6) & 1;
    const int gg  = (G >> 4) & 3;
    const int ll  = G & 15;

    const size_t dst = ((size_t)(b * NIT + kt) * GR_TILE + G) * 8;
    float x[8];
    if (!isV) {
        const float* src = Kg + ((size_t)b * LKK + kt * KBLK + 16 * blk + ll) * DH + 32 * c + 8 * gg;
        float4 a0 = *(const float4*)src;
        float4 a1 = *(const float4*)(src + 4);
        x[0]=a0.x; x[1]=a0.y; x[2]=a0.z; x[3]=a0.w;
        x[4]=a1.x; x[5]=a1.y; x[6]=a1.z; x[7]=a1.w;
        bf16x8 h, l;
#pragma unroll
        for (int j = 0; j < 8; ++j) {
            __bf16 hh = (__bf16)x[j];
            h[j] = hh; l[j] = (__bf16)(x[j] - (float)hh);
        }
        *(bf16x8*)&KHI[dst] = h;  *(bf16x8*)&KLO[dst] = l;
    } else {
        const float* src = Vg + ((size_t)b * LKK + kt * KBLK + 32 * c + 8 * gg) * DH + 16 * blk + ll;
#pragma unroll
        for (int j = 0; j < 8; ++j) x[j] = src[(size_t)j * DH];
        bf16x8 h, l;
#pragma unroll
        for (int j = 0; j < 8; ++j) {
            __bf16 hh = (__bf16)x[j];
            h[j] = hh; l[j] = (__bf16)(x[j] - (float)hh);
        }
        *(bf16x8*)&VHI[dst] = h;  *(bf16x8*)&VLO[dst] = l;
    }
}

// ============== split-KV pass 1: grid 512, 2 blocks/CU, 8 waves/CU ==========
__global__ __launch_bounds__(256, 2)
void attn_split(const float* __restrict__ Qg, const __bf16* __restrict__ ws,
                float* __restrict__ PO, float* __restrict__ PML)
{
    // bid&7 = XCD. h=bid&1, bz=(bid>>1)&3: batch bz's half-h packed KV (1MB)
    // pinned to one XCD's 4MB L2.
    const int bid = blockIdx.x;
    const int h   = bid & 1;
    const int bz  = (bid >> 1) & 3;
    const int qt  = bid >> 3;
    const int pb  = h * 256 + bz * 64 + qt;
    const int tid  = threadIdx.x;
    const int w    = tid >> 6;
    const int lane = tid & 63;
    const int g    = lane >> 4;
    const int l15  = lane & 15;
    const int q0   = qt * QBLK + w * 16;

    __shared__ __align__(16) __bf16 TILES[2][4][GR_TILE * 8];     // 64 KB
    __shared__ __align__(16) unsigned int PSM[4][16 * 64];        // 16 KB

    const __bf16* wsA[4] = { ws, ws + ARR_ELEMS, ws + 2 * ARR_ELEMS, ws + 3 * ARR_ELEMS };
    const size_t bqoff = (size_t)bz * LQ * DH;

    bf16x8 qhi[2], qlo[2];
#pragma unroll
    for (int c = 0; c < 2; ++c) {
        const float* src = Qg + bqoff + (size_t)(q0 + l15) * DH + 32 * c + 8 * g;
#pragma unroll
        for (int j = 0; j < 8; ++j) {
            float x = src[j] * 0.125f;
            __bf16 hh = (__bf16)x;
            qhi[c][j] = hh;
            qlo[c][j] = (__bf16)(x - (float)hh);
        }
    }

    auto STAGE = [&](int buf, int kt) {
        const size_t toff = (size_t)(bz * NIT + kt) * GR_TILE * 8;
#pragma unroll
        for (int a = 0; a < 4; ++a) {
            const __bf16* src = wsA[a] + toff + (size_t)(w * 128 + lane) * 8;
            __bf16* dst = &TILES[buf][a][w * 128 * 8];
            gload_lds16(src, dst);
            gload_lds16(src + 64 * 8, dst + 64 * 8);
        }
    };

    f32x4 oacc[4] = {};
    float m_run[4], l_run[4];
#pragma unroll
    for (int r = 0; r < 4; ++r) { m_run[r] = -1e30f; l_run[r] = 0.f; }

    const int kt0 = h * (NIT / 2);        // 32 tiles per half
    STAGE(0, kt0);
    __syncthreads();

    int cur = 0;
    for (int it = 0; it < NIT / 2; ++it) {
        if (it + 1 < NIT / 2) STAGE(cur ^ 1, kt0 + it + 1);

        const __bf16* KHI_l = TILES[cur][0];
        const __bf16* KLO_l = TILES[cur][1];
        const __bf16* VHI_l = TILES[cur][2];
        const __bf16* VLO_l = TILES[cur][3];

        f32x4 s[4] = {};
        __builtin_amdgcn_s_setprio(1);
#pragma unroll
        for (int kb = 0; kb < 4; ++kb) {
#pragma unroll
            for (int c = 0; c < 2; ++c) {
                bf16x8 kh = *(const bf16x8*)&KHI_l[((kb * 2 + c) * 64 + lane) * 8];
                bf16x8 kl = *(const bf16x8*)&KLO_l[((kb * 2 + c) * 64 + lane) * 8];
                s[kb] = __builtin_amdgcn_mfma_f32_16x16x32_bf16(qhi[c], kh, s[kb], 0, 0, 0);
                s[kb] = __builtin_amdgcn_mfma_f32_16x16x32_bf16(qlo[c], kh, s[kb], 0, 0, 0);
                s[kb] = __builtin_amdgcn_mfma_f32_16x16x32_bf16(qhi[c], kl, s[kb], 0, 0, 0);
            }
        }
        __builtin_amdgcn_s_setprio(0);

        float tmax[4];
#pragma unroll
        for (int r = 0; r < 4; ++r)
            tmax[r] = fmaxf(fmaxf(s[0][r], s[1][r]), fmaxf(s[2][r], s[3][r]));
#pragma unroll
        for (int off = 1; off < 16; off <<= 1)
#pragma unroll
            for (int r = 0; r < 4; ++r)
                tmax[r] = fmaxf(tmax[r], __shfl_xor(tmax[r], off, 64));

        float alpha[4], psum[4];
#pragma unroll
        for (int r = 0; r < 4; ++r) {
            float mnew = fmaxf(m_run[r], tmax[r]);
            alpha[r] = __expf(m_run[r] - mnew);
            m_run[r] = mnew;
            psum[r] = 0.f;
        }
#pragma unroll
        for (int kb = 0; kb < 4; ++kb)
#pragma unroll
            for (int r = 0; r < 4; ++r) {
                float p = __expf(s[kb][r] - m_run[r]);
                s[kb][r] = p;
                psum[r] += p;
            }
#pragma unroll
        for (int off = 1; off < 16; off <<= 1)
#pragma unroll
            for (int r = 0; r < 4; ++r)
                psum[r] += __shfl_xor(psum[r], off, 64);
#pragma unroll
        for (int r = 0; r < 4; ++r) {
            l_run[r] = l_run[r] * alpha[r] + psum[r];
#pragma unroll
            for (int db = 0; db < 4; ++db) oacc[db][r] *= alpha[r];
        }

#pragma unroll
        for (int kb = 0; kb < 4; ++kb)
#pragma unroll
            for (int r = 0; r < 4; ++r) {
                float p = s[kb][r];
                __bf16 hh = (__bf16)p;
                __bf16 ll2 = (__bf16)(p - (float)hh);
                const int row = 4 * g + r;
                const int idx = row * 64 + (((4 * kb + (l15 >> 2) + row) & 15) << 2) + (l15 & 3);
                PSM[w][idx] = (unsigned int)bf2u(hh) | ((unsigned int)bf2u(ll2) << 16);
            }

#pragma unroll
        for (int c = 0; c < 2; ++c) {
            const unsigned int* prow = &PSM[w][l15 * 64];
            const int qg = 2 * g + 8 * c;
            uint4 ulo = *(const uint4*)&prow[((qg + l15) & 15) << 2];
            uint4 uhi = *(const uint4*)&prow[((qg + 1 + l15) & 15) << 2];
            unsigned int uu[8] = { ulo.x, ulo.y, ulo.z, ulo.w, uhi.x, uhi.y, uhi.z, uhi.w };
            bf16x8 ph, pl;
#pragma unroll
            for (int j = 0; j < 8; ++j) {
                ph[j] = u2bf((unsigned short)(uu[j] & 0xffffu));
                pl[j] = u2bf((unsigned short)(uu[j] >> 16));
            }
            __builtin_amdgcn_s_setprio(1);
#pragma unroll
            for (int db = 0; db < 4; ++db) {
                bf16x8 vh = *(const bf16x8*)&VHI_l[((db * 2 + c) * 64 + lane) * 8];
                bf16x8 vl = *(const bf16x8*)&VLO_l[((db * 2 + c) * 64 + lane) * 8];
                oacc[db] = __builtin_amdgcn_mfma_f32_16x16x32_bf16(ph, vh, oacc[db], 0, 0, 0);
                oacc[db] = __builtin_amdgcn_mfma_f32_16x16x32_bf16(ph, vl, oacc[db], 0, 0, 0);
                oacc[db] = __builtin_amdgcn_mfma_f32_16x16x32_bf16(pl, vh, oacc[db], 0, 0, 0);
            }
            __builtin_amdgcn_s_setprio(0);
        }

        __syncthreads();
        cur ^= 1;
    }

    // ---- partial epilogue: unnormalized O~ + (m,l). Row = w*16 + 4g + r ----
    float* po = PO + (size_t)pb * (QBLK * DH);
    const int rbase = w * 16;
#pragma unroll
    for (int r = 0; r < 4; ++r)
#pragma unroll
        for (int db = 0; db < 4; ++db)
            po[(rbase + 4 * g + r) * DH + 16 * db + l15] = oacc[db][r];
    if (l15 == 0) {
#pragma unroll
        for (int r = 0; r < 4; ++r) {
            PML[pb * 128 + rbase + 4 * g + r]      = m_run[r];
            PML[pb * 128 + 64 + rbase + 4 * g + r] = l_run[r];
        }
    }
}

__global__ __launch_bounds__(256)
void combine(const float* __restrict__ PO, const float* __restrict__ PML,
             float* __restrict__ Og)
{
    const int t  = blockIdx.x * 256 + threadIdx.x;   // [0, 1048576)
    const int d   = t & 63;
    const int row = (t >> 6) & 4095;
    const int bz  = t >> 18;
    const int qt  = row >> 6, ri = row & 63;
    const int pb0 = bz * 64 + qt;
    const int pb1 = 256 + pb0;
    float m0 = PML[pb0 * 128 + ri], l0 = PML[pb0 * 128 + 64 + ri];
    float m1 = PML[pb1 * 128 + ri], l1 = PML[pb1 * 128 + 64 + ri];
    float M  = fmaxf(m0, m1);
    float a0 = __expf(m0 - M), a1 = __expf(m1 - M);
    float o0 = PO[(size_t)pb0 * 4096 + ri * 64 + d];
    float o1 = PO[(size_t)pb1 * 4096 + ri * 64 + d];
    Og[t] = (a0 * o0 + a1 * o1) / (a0 * l0 + a1 * l1);
}

// ============== fallback: round-3 single-pass (proven, 146us) ===============
__global__ __launch_bounds__(256, 1)
void attn_fwd_pre(const float* __restrict__ Qg, const __bf16* __restrict__ ws,
                  float* __restrict__ Og)
{
    const int bid = blockIdx.x;
    const int bz  = (bid >> 1) & 3;
    const int qt  = ((bid & 1) << 5) | (bid >> 3);
    const int tid  = threadIdx.x;
    const int w    = tid >> 6;
    const int lane = tid & 63;
    const int g    = lane >> 4;
    const int l15  = lane & 15;
    const int q0   = qt * QBLK + w * 16;

    __shared__ __align__(16) __bf16 TILES[2][4][GR_TILE * 8];
    __shared__ __align__(16) unsigned int PSM[4][16 * 64];

    const __bf16* wsA[4] = { ws, ws + ARR_ELEMS, ws + 2 * ARR_ELEMS, ws + 3 * ARR_ELEMS };
    const size_t bqoff = (size_t)bz * LQ * DH;

    bf16x8 qhi[2], qlo[2];
#pragma unroll
    for (int c = 0; c < 2; ++c) {
        const float* src = Qg + bqoff + (size_t)(q0 + l15) * DH + 32 * c + 8 * g;
#pragma unroll
        for (int j = 0; j < 8; ++j) {
            float x = src[j] * 0.125f;
            __bf16 hh = (__bf16)x;
            qhi[c][j] = hh;
            qlo[c][j] = (__bf16)(x - (float)hh);
        }
    }

    auto STAGE = [&](int buf, int kt) {
        const size_t toff = (size_t)(bz * NIT + kt) * GR_TILE * 8;
#pragma unroll
        for (int a = 0; a < 4; ++a) {
            const __bf16* src = wsA[a] + toff + (size_t)(w * 128 + lane) * 8;
            __bf16* dst = &TILES[buf][a][w * 128 * 8];
            gload_lds16(src, dst);
            gload_lds16(src + 64 * 8, dst + 64 * 8);
        }
    };

    f32x4 oacc[4] = {};
    float m_run[4], l_run[4];
#pragma unroll
    for (int r = 0; r < 4; ++r) { m_run[r] = -1e30f; l_run[r] = 0.f; }

    STAGE(0, 0);
    __syncthreads();

    int cur = 0;
    for (int kt = 0; kt < NIT; ++kt) {
        if (kt + 1 < NIT) STAGE(cur ^ 1, kt + 1);

        const __bf16* KHI_l = TILES[cur][0];
        const __bf16* KLO_l = TILES[cur][1];
        const __bf16* VHI_l = TILES[cur][2];
        const __bf16* VLO_l = TILES[cur][3];

        f32x4 s[4] = {};
        __builtin_amdgcn_s_setprio(1);
#pragma unroll
        for (int kb = 0; kb < 4; ++kb) {
#pragma unroll
            for (int c = 0; c < 2; ++c) {
                bf16x8 kh = *(const bf16x8*)&KHI_l[((kb * 2 + c) * 64 + lane) * 8];
                bf16x8 kl = *(const bf16x8*)&KLO_l[((kb * 2 + c) * 64 + lane) * 8];
                s[kb] = __builtin_amdgcn_mfma_f32_16x16x32_bf16(qhi[c], kh, s[kb], 0, 0, 0);
                s[kb] = __builtin_amdgcn_mfma_f32_16x16x32_bf16(qlo[c], kh, s[kb], 0, 0, 0);
                s[kb] = __builtin_amdgcn_mfma_f32_16x16x32_bf16(qhi[c], kl, s[kb], 0, 0, 0);
            }
        }
        __builtin_amdgcn_s_setprio(0);

        float tmax[4];
#pragma unroll
        for (int r = 0; r < 4; ++r)
            tmax[r] = fmaxf(fmaxf(s[0][r], s[1][r]), fmaxf(s[2][r], s[3][r]));
#pragma unroll
        for (int off = 1; off < 16; off <<= 1)
#pragma unroll
            for (int r = 0; r < 4; ++r)
                tmax[r] = fmaxf(tmax[r], __shfl_xor(tmax[r], off, 64));

        float alpha[4], psum[4];
#pragma unroll
        for (int r = 0; r < 4; ++r) {
            float mnew = fmaxf(m_run[r], tmax[r]);
            alpha[r] = __expf(m_run[r] - mnew);
            m_run[r] = mnew;
            psum[r] = 0.f;
        }
#pragma unroll
        for (int kb = 0; kb < 4; ++kb)
#pragma unroll
            for (int r = 0; r < 4; ++r) {
                float p = __expf(s[kb][r] - m_run[r]);
                s[kb][r] = p;
                psum[r] += p;
            }
#pragma unroll
        for (int off = 1; off < 16; off <<= 1)
#pragma unroll
            for (int r = 0; r < 4; ++r)
                psum[r] += __shfl_xor(psum[r], off, 64);
#pragma unroll
        for (int r = 0; r < 4; ++r) {
            l_run[r] = l_run[r] * alpha[r] + psum[r];
#pragma unroll
            for (int db = 0; db < 4; ++db) oacc[db][r] *= alpha[r];
        }

#pragma unroll
        for (int kb = 0; kb < 4; ++kb)
#pragma unroll
            for (int r = 0; r < 4; ++r) {
                float p = s[kb][r];
                __bf16 hh = (__bf16)p;
                __bf16 ll2 = (__bf16)(p - (float)hh);
                const int row = 4 * g + r;
                const int idx = row * 64 + (((4 * kb + (l15 >> 2) + row) & 15) << 2) + (l15 & 3);
                PSM[w][idx] = (unsigned int)bf2u(hh) | ((unsigned int)bf2u(ll2) << 16);
            }

#pragma unroll
        for (int c = 0; c < 2; ++c) {
            const unsigned int* prow = &PSM[w][l15 * 64];
            const int qg = 2 * g + 8 * c;
            uint4 ulo = *(const uint4*)&prow[((qg + l15) & 15) << 2];
            uint4 uhi = *(const uint4*)&prow[((qg + 1 + l15) & 15) << 2];
            unsigned int uu[8] = { ulo.x, ulo.y, ulo.z, ulo.w, uhi.x, uhi.y, uhi.z, uhi.w };
            bf16x8 ph, pl;
#pragma unroll
            for (int j = 0; j < 8; ++j) {
                ph[j] = u2bf((unsigned short)(uu[j] & 0xffffu));
                pl[j] = u2bf((unsigned short)(uu[j] >> 16));
            }
            __builtin_amdgcn_s_setprio(1);
#pragma unroll
            for (int db = 0; db < 4; ++db) {
                bf16x8 vh = *(const bf16x8*)&VHI_l[((db * 2 + c) * 64 + lane) * 8];
                bf16x8 vl = *(const bf16x8*)&VLO_l[((db * 2 + c) * 64 + lane) * 8];
                oacc[db] = __builtin_amdgcn_mfma_f32_16x16x32_bf16(ph, vh, oacc[db], 0, 0, 0);
                oacc[db] = __builtin_amdgcn_mfma_f32_16x16x32_bf16(ph, vl, oacc[db], 0, 0, 0);
                oacc[db] = __builtin_amdgcn_mfma_f32_16x16x32_bf16(pl, vh, oacc[db], 0, 0, 0);
            }
            __builtin_amdgcn_s_setprio(0);
        }

        __syncthreads();
        cur ^= 1;
    }

#pragma unroll
    for (int r = 0; r < 4; ++r) {
        float inv = 1.0f / l_run[r];
#pragma unroll
        for (int db = 0; db < 4; ++db)
            Og[bqoff + (size_t)(q0 + 4 * g + r) * DH + 16 * db + l15] = oacc[db][r] * inv;
    }
}

extern "C" void kernel_launch(void* const* d_in, const int* in_sizes, int n_in,
                              void* d_out, int out_size, void* d_ws, size_t ws_size,
                              hipStream_t stream) {
    (void)in_sizes; (void)n_in; (void)out_size;
    const float* Q = (const float*)d_in[0];
    const float* K = (const float*)d_in[1];
    const float* V = (const float*)d_in[2];
    float* O = (float*)d_out;

    if (ws_size >= WS_SPLIT) {
        __bf16* ws = (__bf16*)d_ws;
        float* PO  = (float*)((char*)d_ws + KV_BYTES);
        float* PML = (float*)((char*)d_ws + KV_BYTES + PO_BYTES);
        prepack<<<dim3(1024), dim3(256), 0, stream>>>(K, V, ws);
        attn_split<<<dim3(512), dim3(256), 0, stream>>>(Q, ws, PO, PML);
        combine<<<dim3(4096), dim3(256), 0, stream>>>(PO, PML, O);
    } else if (ws_size >= WS_SINGLE) {
        __bf16* ws = (__bf16*)d_ws;
        prepack<<<dim3(1024), dim3(256), 0, stream>>>(K, V, ws);
        attn_fwd_pre<<<dim3(256), dim3(256), 0, stream>>>(Q, ws, O);
    }
}

// Round 7
// 132.688 us; speedup vs baseline: 1.5257x; 1.1869x over previous
//
#include <hip/hip_runtime.h>
#include <hip/hip_bf16.h>

typedef __bf16 bf16x8 __attribute__((ext_vector_type(8)));
typedef float  f32x4  __attribute__((ext_vector_type(4)));

#define LQ 4096
#define LKK 4096
#define DH 64
#define KBLK 64
#define QBLK 64
#define NIT (LKK / KBLK)        /* 64 KV tiles */
#define NB 4                    /* batch */
#define GR_TILE 512             /* 16B granules per 64x64 bf16 tile */
#define ARR_ELEMS ((size_t)NB * NIT * GR_TILE * 8)   /* 1,048,576 per array */
#define KV_BYTES (4 * ARR_ELEMS * sizeof(__bf16))    /* 8 MB packed KV */
#define PO_BYTES ((size_t)512 * 4096 * sizeof(float))   /* 8 MB partial O */
#define PML_BYTES ((size_t)512 * 128 * sizeof(float))   /* 256 KB m,l */
#define WS_SPLIT (KV_BYTES + PO_BYTES + PML_BYTES)      /* 16.25 MB */
#define WS_SINGLE KV_BYTES

union BFU { unsigned short u; __bf16 b; };
__device__ __forceinline__ __bf16 u2bf(unsigned short v) { BFU x; x.u = v; return x.b; }
__device__ __forceinline__ unsigned short bf2u(__bf16 b) { BFU x; x.b = b; return x.u; }

typedef const __attribute__((address_space(1))) void* gas1_t;
typedef __attribute__((address_space(3))) void* las3_t;
__device__ __forceinline__ void gload_lds16(const void* g, void* l) {
    __builtin_amdgcn_global_load_lds((gas1_t)g, (las3_t)l, 16, 0, 0);
}

// v_cvt_pk_bf16_f32: packs 2 f32 -> u32 of 2 bf16 (RNE). No builtin on gfx950.
__device__ __forceinline__ unsigned cvt_pk_bf16(float a, float b) {
    unsigned r;
    asm volatile("v_cvt_pk_bf16_f32 %0, %1, %2" : "=v"(r) : "v"(a), "v"(b));
    return r;
}

// ---------------------------------------------------------------------------
// Fragment-linear layout (granule = 16B = one lane's ds_read_b128):
//   K granule G=(kb*2+c)*64+ln, elem j = K[16*kb + ll][32*c + 8*gg + j]
//   V granule G=(db*2+c)*64+ln, elem j = V[32*c + 8*gg + j][16*db + ll]
// with gg=ln>>4, ll=ln&15.
//
// SWAPPED-OPERAND SCHEME (this round): the same granules serve as the
// *A*-operand of mfma(K,Q) -> S^T and mfma(V,P) -> O^T:
//   S^T: lane holds q=l15, keys = 16kb+4g+r  (softmax in-lane + 2 shfl)
//   O^T: lane holds q=l15, d = 16db+4g+r     (rescale lane-uniform)
// P redistribution via per-wave PSM of bf16 pair-words:
//   logical word w (hi: w=key>>1 in [0,32); lo: +32), phys = w ^ ((q&7)<<2)
//   -> reads are 4 aligned ds_read_b128 at the bandwidth floor.
// ---------------------------------------------------------------------------

__global__ __launch_bounds__(256)
void prepack(const float* __restrict__ Kg, const float* __restrict__ Vg,
             __bf16* __restrict__ ws)
{
    __bf16* KHI = ws;
    __bf16* KLO = ws + ARR_ELEMS;
    __bf16* VHI = ws + 2 * ARR_ELEMS;
    __bf16* VLO = ws + 3 * ARR_ELEMS;

    const int gid = blockIdx.x * 256 + threadIdx.x;   // [0, 262144)
    const int isV = gid >> 17;
    const int t   = gid & 131071;
    const int b   = t >> 15;
    const int rem = t & 32767;
    const int kt  = rem >> 9;
    const int G   = rem & 511;
    const int blk = G >> 7;
    const int c   = (G >> 6) & 1;
    const int gg  = (G >> 4) & 3;
    const int ll  = G & 15;

    const size_t dst = ((size_t)(b * NIT + kt) * GR_TILE + G) * 8;
    float x[8];
    if (!isV) {
        const float* src = Kg + ((size_t)b * LKK + kt * KBLK + 16 * blk + ll) * DH + 32 * c + 8 * gg;
        float4 a0 = *(const float4*)src;
        float4 a1 = *(const float4*)(src + 4);
        x[0]=a0.x; x[1]=a0.y; x[2]=a0.z; x[3]=a0.w;
        x[4]=a1.x; x[5]=a1.y; x[6]=a1.z; x[7]=a1.w;
        bf16x8 h, l;
#pragma unroll
        for (int j = 0; j < 8; ++j) {
            __bf16 hh = (__bf16)x[j];
            h[j] = hh; l[j] = (__bf16)(x[j] - (float)hh);
        }
        *(bf16x8*)&KHI[dst] = h;  *(bf16x8*)&KLO[dst] = l;
    } else {
        const float* src = Vg + ((size_t)b * LKK + kt * KBLK + 32 * c + 8 * gg) * DH + 16 * blk + ll;
#pragma unroll
        for (int j = 0; j < 8; ++j) x[j] = src[(size_t)j * DH];
        bf16x8 h, l;
#pragma unroll
        for (int j = 0; j < 8; ++j) {
            __bf16 hh = (__bf16)x[j];
            h[j] = hh; l[j] = (__bf16)(x[j] - (float)hh);
        }
        *(bf16x8*)&VHI[dst] = h;  *(bf16x8*)&VLO[dst] = l;
    }
}

// ============== split-KV pass 1: swapped-operand, in-lane softmax ===========
__global__ __launch_bounds__(256, 2)
void attn_split(const float* __restrict__ Qg, const __bf16* __restrict__ ws,
                float* __restrict__ PO, float* __restrict__ PML)
{
    const int bid = blockIdx.x;
    const int h   = bid & 1;
    const int bz  = (bid >> 1) & 3;
    const int qt  = bid >> 3;
    const int pb  = h * 256 + bz * 64 + qt;
    const int tid  = threadIdx.x;
    const int w    = tid >> 6;
    const int lane = tid & 63;
    const int g    = lane >> 4;
    const int l15  = lane & 15;
    const int q0   = qt * QBLK + w * 16;

    __shared__ __align__(16) __bf16 TILES[2][4][GR_TILE * 8];     // 64 KB
    __shared__ __align__(16) unsigned int PSM[4][16 * 64];        // 16 KB

    const __bf16* wsA[4] = { ws, ws + ARR_ELEMS, ws + 2 * ARR_ELEMS, ws + 3 * ARR_ELEMS };
    const size_t bqoff = (size_t)bz * LQ * DH;

    bf16x8 qhi[2], qlo[2];
#pragma unroll
    for (int c = 0; c < 2; ++c) {
        const float* src = Qg + bqoff + (size_t)(q0 + l15) * DH + 32 * c + 8 * g;
#pragma unroll
        for (int j = 0; j < 8; ++j) {
            float x = src[j] * 0.125f;
            __bf16 hh = (__bf16)x;
            qhi[c][j] = hh;
            qlo[c][j] = (__bf16)(x - (float)hh);
        }
    }

    auto STAGE = [&](int buf, int kt) {
        const size_t toff = (size_t)(bz * NIT + kt) * GR_TILE * 8;
#pragma unroll
        for (int a = 0; a < 4; ++a) {
            const __bf16* src = wsA[a] + toff + (size_t)(w * 128 + lane) * 8;
            __bf16* dst = &TILES[buf][a][w * 128 * 8];
            gload_lds16(src, dst);
            gload_lds16(src + 64 * 8, dst + 64 * 8);
        }
    };

    f32x4 oacc[4] = {};
    float m_run = -1e30f, l_run = 0.f;

    const int kt0 = h * (NIT / 2);        // 32 tiles per half
    STAGE(0, kt0);
    __syncthreads();

    int cur = 0;
    const int sw = (l15 & 7) << 2;        // PSM quad swizzle for this lane's q
    const int prow = l15 * 64;

    for (int it = 0; it < NIT / 2; ++it) {
        if (it + 1 < NIT / 2) STAGE(cur ^ 1, kt0 + it + 1);

        const __bf16* KHI_l = TILES[cur][0];
        const __bf16* KLO_l = TILES[cur][1];
        const __bf16* VHI_l = TILES[cur][2];
        const __bf16* VLO_l = TILES[cur][3];

        // ---- S^T = K (Q*scale)^T : A=K granule, B=Q fragment ----
        f32x4 s[4] = {};
        __builtin_amdgcn_s_setprio(1);
#pragma unroll
        for (int kb = 0; kb < 4; ++kb) {
#pragma unroll
            for (int c = 0; c < 2; ++c) {
                bf16x8 kh = *(const bf16x8*)&KHI_l[((kb * 2 + c) * 64 + lane) * 8];
                bf16x8 kl = *(const bf16x8*)&KLO_l[((kb * 2 + c) * 64 + lane) * 8];
                s[kb] = __builtin_amdgcn_mfma_f32_16x16x32_bf16(kh, qhi[c], s[kb], 0, 0, 0);
                s[kb] = __builtin_amdgcn_mfma_f32_16x16x32_bf16(kh, qlo[c], s[kb], 0, 0, 0);
                s[kb] = __builtin_amdgcn_mfma_f32_16x16x32_bf16(kl, qhi[c], s[kb], 0, 0, 0);
            }
        }
        __builtin_amdgcn_s_setprio(0);

        // ---- online softmax: lane owns q=l15; keys 16kb+4g+r in-lane ----
        float tmax = -1e30f;
#pragma unroll
        for (int kb = 0; kb < 4; ++kb)
#pragma unroll
            for (int r = 0; r < 4; ++r)
                tmax = fmaxf(tmax, s[kb][r]);
        tmax = fmaxf(tmax, __shfl_xor(tmax, 16, 64));
        tmax = fmaxf(tmax, __shfl_xor(tmax, 32, 64));

        // T13 defer-max: skip rescale while max growth <= 8 (P bounded e^8)
        const bool defer = __all(tmax <= m_run + 8.f);
        float alpha = 1.f;
        if (!defer) {
            float mnew = fmaxf(m_run, tmax);
            alpha = __expf(m_run - mnew);
            m_run = mnew;
        }

        float psum = 0.f;
#pragma unroll
        for (int kb = 0; kb < 4; ++kb)
#pragma unroll
            for (int r = 0; r < 4; ++r) {
                float p = __expf(s[kb][r] - m_run);
                s[kb][r] = p;
                psum += p;
            }
        psum += __shfl_xor(psum, 16, 64);
        psum += __shfl_xor(psum, 32, 64);

        if (!defer) {
            l_run = l_run * alpha + psum;
#pragma unroll
            for (int db = 0; db < 4; ++db) oacc[db] *= alpha;
        } else {
            l_run += psum;
        }

        // ---- P hi/lo pair-words -> PSM (quad-XOR swizzled) ----
#pragma unroll
        for (int kb = 0; kb < 4; ++kb) {
            unsigned h0 = cvt_pk_bf16(s[kb][0], s[kb][1]);
            unsigned h1 = cvt_pk_bf16(s[kb][2], s[kb][3]);
            float l0 = s[kb][0] - __uint_as_float(h0 << 16);
            float l1 = s[kb][1] - __uint_as_float(h0 & 0xffff0000u);
            float l2 = s[kb][2] - __uint_as_float(h1 << 16);
            float l3 = s[kb][3] - __uint_as_float(h1 & 0xffff0000u);
            unsigned lo0 = cvt_pk_bf16(l0, l1);
            unsigned lo1 = cvt_pk_bf16(l2, l3);
            const int wb = 8 * kb + 2 * g;
            PSM[w][prow + ((wb)     ^ sw)]      = h0;
            PSM[w][prow + ((wb + 1) ^ sw)]      = h1;
            PSM[w][prow + 32 + ((wb)     ^ sw)] = lo0;
            PSM[w][prow + 32 + ((wb + 1) ^ sw)] = lo1;
        }

        // ---- O^T += V^T P^T : A=V granule, B=P fragment (read back b128) ----
#pragma unroll
        for (int c = 0; c < 2; ++c) {
            const int qb = prow + (((4 * c + g) ^ (l15 & 7)) << 2);
            bf16x8 ph = *(const bf16x8*)&PSM[w][qb];
            bf16x8 pl = *(const bf16x8*)&PSM[w][qb + 32];
            __builtin_amdgcn_s_setprio(1);
#pragma unroll
            for (int db = 0; db < 4; ++db) {
                bf16x8 vh = *(const bf16x8*)&VHI_l[((db * 2 + c) * 64 + lane) * 8];
                bf16x8 vl = *(const bf16x8*)&VLO_l[((db * 2 + c) * 64 + lane) * 8];
                oacc[db] = __builtin_amdgcn_mfma_f32_16x16x32_bf16(vh, ph, oacc[db], 0, 0, 0);
                oacc[db] = __builtin_amdgcn_mfma_f32_16x16x32_bf16(vl, ph, oacc[db], 0, 0, 0);
                oacc[db] = __builtin_amdgcn_mfma_f32_16x16x32_bf16(vh, pl, oacc[db], 0, 0, 0);
            }
            __builtin_amdgcn_s_setprio(0);
        }

        __syncthreads();
        cur ^= 1;
    }

    // ---- partial epilogue: lane q = w*16+l15, oacc[db] = d 16db+4g..+3 ----
    float* po = PO + (size_t)pb * (QBLK * DH) + (size_t)(w * 16 + l15) * DH;
#pragma unroll
    for (int db = 0; db < 4; ++db)
        *(f32x4*)&po[16 * db + 4 * g] = oacc[db];
    if (g == 0) {
        PML[pb * 128 + w * 16 + l15]      = m_run;
        PML[pb * 128 + 64 + w * 16 + l15] = l_run;
    }
}

__global__ __launch_bounds__(256)
void combine(const float* __restrict__ PO, const float* __restrict__ PML,
             float* __restrict__ Og)
{
    const int t  = blockIdx.x * 256 + threadIdx.x;   // [0, 1048576)
    const int d   = t & 63;
    const int row = (t >> 6) & 4095;
    const int bz  = t >> 18;
    const int qt  = row >> 6, ri = row & 63;
    const int pb0 = bz * 64 + qt;
    const int pb1 = 256 + pb0;
    float m0 = PML[pb0 * 128 + ri], l0 = PML[pb0 * 128 + 64 + ri];
    float m1 = PML[pb1 * 128 + ri], l1 = PML[pb1 * 128 + 64 + ri];
    float M  = fmaxf(m0, m1);
    float a0 = __expf(m0 - M), a1 = __expf(m1 - M);
    float o0 = PO[(size_t)pb0 * 4096 + ri * 64 + d];
    float o1 = PO[(size_t)pb1 * 4096 + ri * 64 + d];
    Og[t] = (a0 * o0 + a1 * o1) / (a0 * l0 + a1 * l1);
}

// ============== fallback: round-3 single-pass (proven, unused if ws ok) =====
__global__ __launch_bounds__(256, 1)
void attn_fwd_pre(const float* __restrict__ Qg, const __bf16* __restrict__ ws,
                  float* __restrict__ Og)
{
    const int bid = blockIdx.x;
    const int bz  = (bid >> 1) & 3;
    const int qt  = ((bid & 1) << 5) | (bid >> 3);
    const int tid  = threadIdx.x;
    const int w    = tid >> 6;
    const int lane = tid & 63;
    const int g    = lane >> 4;
    const int l15  = lane & 15;
    const int q0   = qt * QBLK + w * 16;

    __shared__ __align__(16) __bf16 TILES[2][4][GR_TILE * 8];
    __shared__ __align__(16) unsigned int PSM[4][16 * 64];

    const __bf16* wsA[4] = { ws, ws + ARR_ELEMS, ws + 2 * ARR_ELEMS, ws + 3 * ARR_ELEMS };
    const size_t bqoff = (size_t)bz * LQ * DH;

    bf16x8 qhi[2], qlo[2];
#pragma unroll
    for (int c = 0; c < 2; ++c) {
        const float* src = Qg + bqoff + (size_t)(q0 + l15) * DH + 32 * c + 8 * g;
#pragma unroll
        for (int j = 0; j < 8; ++j) {
            float x = src[j] * 0.125f;
            __bf16 hh = (__bf16)x;
            qhi[c][j] = hh;
            qlo[c][j] = (__bf16)(x - (float)hh);
        }
    }

    auto STAGE = [&](int buf, int kt) {
        const size_t toff = (size_t)(bz * NIT + kt) * GR_TILE * 8;
#pragma unroll
        for (int a = 0; a < 4; ++a) {
            const __bf16* src = wsA[a] + toff + (size_t)(w * 128 + lane) * 8;
            __bf16* dst = &TILES[buf][a][w * 128 * 8];
            gload_lds16(src, dst);
            gload_lds16(src + 64 * 8, dst + 64 * 8);
        }
    };

    f32x4 oacc[4] = {};
    float m_run[4], l_run[4];
#pragma unroll
    for (int r = 0; r < 4; ++r) { m_run[r] = -1e30f; l_run[r] = 0.f; }

    STAGE(0, 0);
    __syncthreads();

    int cur = 0;
    for (int kt = 0; kt < NIT; ++kt) {
        if (kt + 1 < NIT) STAGE(cur ^ 1, kt + 1);

        const __bf16* KHI_l = TILES[cur][0];
        const __bf16* KLO_l = TILES[cur][1];
        const __bf16* VHI_l = TILES[cur][2];
        const __bf16* VLO_l = TILES[cur][3];

        f32x4 s[4] = {};
#pragma unroll
        for (int kb = 0; kb < 4; ++kb) {
#pragma unroll
            for (int c = 0; c < 2; ++c) {
                bf16x8 kh = *(const bf16x8*)&KHI_l[((kb * 2 + c) * 64 + lane) * 8];
                bf16x8 kl = *(const bf16x8*)&KLO_l[((kb * 2 + c) * 64 + lane) * 8];
                s[kb] = __builtin_amdgcn_mfma_f32_16x16x32_bf16(qhi[c], kh, s[kb], 0, 0, 0);
                s[kb] = __builtin_amdgcn_mfma_f32_16x16x32_bf16(qlo[c], kh, s[kb], 0, 0, 0);
                s[kb] = __builtin_amdgcn_mfma_f32_16x16x32_bf16(qhi[c], kl, s[kb], 0, 0, 0);
            }
        }

        float tmax[4];
#pragma unroll
        for (int r = 0; r < 4; ++r)
            tmax[r] = fmaxf(fmaxf(s[0][r], s[1][r]), fmaxf(s[2][r], s[3][r]));
#pragma unroll
        for (int off = 1; off < 16; off <<= 1)
#pragma unroll
            for (int r = 0; r < 4; ++r)
                tmax[r] = fmaxf(tmax[r], __shfl_xor(tmax[r], off, 64));

        float alpha[4], psum[4];
#pragma unroll
        for (int r = 0; r < 4; ++r) {
            float mnew = fmaxf(m_run[r], tmax[r]);
            alpha[r] = __expf(m_run[r] - mnew);
            m_run[r] = mnew;
            psum[r] = 0.f;
        }
#pragma unroll
        for (int kb = 0; kb < 4; ++kb)
#pragma unroll
            for (int r = 0; r < 4; ++r) {
                float p = __expf(s[kb][r] - m_run[r]);
                s[kb][r] = p;
                psum[r] += p;
            }
#pragma unroll
        for (int off = 1; off < 16; off <<= 1)
#pragma unroll
            for (int r = 0; r < 4; ++r)
                psum[r] += __shfl_xor(psum[r], off, 64);
#pragma unroll
        for (int r = 0; r < 4; ++r) {
            l_run[r] = l_run[r] * alpha[r] + psum[r];
#pragma unroll
            for (int db = 0; db < 4; ++db) oacc[db][r] *= alpha[r];
        }

#pragma unroll
        for (int kb = 0; kb < 4; ++kb)
#pragma unroll
            for (int r = 0; r < 4; ++r) {
                float p = s[kb][r];
                __bf16 hh = (__bf16)p;
                __bf16 ll2 = (__bf16)(p - (float)hh);
                const int row = 4 * g + r;
                const int idx = row * 64 + (((4 * kb + (l15 >> 2) + row) & 15) << 2) + (l15 & 3);
                PSM[w][idx] = (unsigned int)bf2u(hh) | ((unsigned int)bf2u(ll2) << 16);
            }

#pragma unroll
        for (int c = 0; c < 2; ++c) {
            const unsigned int* prow2 = &PSM[w][l15 * 64];
            const int qg = 2 * g + 8 * c;
            uint4 ulo = *(const uint4*)&prow2[((qg + l15) & 15) << 2];
            uint4 uhi = *(const uint4*)&prow2[((qg + 1 + l15) & 15) << 2];
            unsigned int uu[8] = { ulo.x, ulo.y, ulo.z, ulo.w, uhi.x, uhi.y, uhi.z, uhi.w };
            bf16x8 ph, pl;
#pragma unroll
            for (int j = 0; j < 8; ++j) {
                ph[j] = u2bf((unsigned short)(uu[j] & 0xffffu));
                pl[j] = u2bf((unsigned short)(uu[j] >> 16));
            }
#pragma unroll
            for (int db = 0; db < 4; ++db) {
                bf16x8 vh = *(const bf16x8*)&VHI_l[((db * 2 + c) * 64 + lane) * 8];
                bf16x8 vl = *(const bf16x8*)&VLO_l[((db * 2 + c) * 64 + lane) * 8];
                oacc[db] = __builtin_amdgcn_mfma_f32_16x16x32_bf16(ph, vh, oacc[db], 0, 0, 0);
                oacc[db] = __builtin_amdgcn_mfma_f32_16x16x32_bf16(ph, vl, oacc[db], 0, 0, 0);
                oacc[db] = __builtin_amdgcn_mfma_f32_16x16x32_bf16(pl, vh, oacc[db], 0, 0, 0);
            }
        }

        __syncthreads();
        cur ^= 1;
    }

#pragma unroll
    for (int r = 0; r < 4; ++r) {
        float inv = 1.0f / l_run[r];
#pragma unroll
        for (int db = 0; db < 4; ++db)
            Og[bqoff + (size_t)(q0 + 4 * g + r) * DH + 16 * db + l15] = oacc[db][r] * inv;
    }
}

extern "C" void kernel_launch(void* const* d_in, const int* in_sizes, int n_in,
                              void* d_out, int out_size, void* d_ws, size_t ws_size,
                              hipStream_t stream) {
    (void)in_sizes; (void)n_in; (void)out_size;
    const float* Q = (const float*)d_in[0];
    const float* K = (const float*)d_in[1];
    const float* V = (const float*)d_in[2];
    float* O = (float*)d_out;

    if (ws_size >= WS_SPLIT) {
        __bf16* ws = (__bf16*)d_ws;
        float* PO  = (float*)((char*)d_ws + KV_BYTES);
        float* PML = (float*)((char*)d_ws + KV_BYTES + PO_BYTES);
        prepack<<<dim3(1024), dim3(256), 0, stream>>>(K, V, ws);
        attn_split<<<dim3(512), dim3(256), 0, stream>>>(Q, ws, PO, PML);
        combine<<<dim3(4096), dim3(256), 0, stream>>>(PO, PML, O);
    } else if (ws_size >= WS_SINGLE) {
        __bf16* ws = (__bf16*)d_ws;
        prepack<<<dim3(1024), dim3(256), 0, stream>>>(K, V, ws);
        attn_fwd_pre<<<dim3(256), dim3(256), 0, stream>>>(Q, ws, O);
    }
}